// Round 9
// baseline (476.832 us; speedup 1.0000x reference)
//
#include <hip/hip_runtime.h>
#include <hip/hip_cooperative_groups.h>

namespace cg = cooperative_groups;

// GNB dispersion — Round 9: single cooperative persistent kernel, 5 phases:
//   0 init (zero cn/cursor/ovf + isCN bitmask + PT table)
//   1 scatter (round-7 reload structure: histogram+degree / scan / sort-in-LDS /
//     coalesced bucket stores)  [TILE=4096, 512 thr, no reg-held tile -> no spill]
//   2 params (pid class per node)
//   3 energy (per (bin,slice) LDS accumulate + pid gather; ovf tail items)
//   4 reduce (out = ovf + sum of slice replicas)
// grid.sync() between phases; fallback = 5 separate launches of the same kernel.
// Record: uint2{ x = s | (r&1023)<<17, y = len bits }; bucket id = r>>10.
// Assumes n_nodes <= 131072 (17-bit ids), NB2 <= 128.

#define B2SHIFT 10
#define B2SIZE  1024
#define TILE    4096
#define SBLK    512
#define ES      16
#define MAXB    128
#define OVB     8

__device__ __constant__ float2 GNB_RC6[87] = {
    {0.f, 0.f},
    {3.6516f, 95.99f},   {2.1843f, 40.67f},   {1.2711f, 70.21f},
    {3.3497f, 114.51f},  {2.7079f, 152.36f},  {1.8219f, 184.28f},
    {2.4667f, 482.54f},  {2.365f, 405.57f},   {1.5062f, 218.45f},
    {1.8233f, 174.81f},  {1.3974f, 181.7f},   {3.3515f, 263.02f},
    {3.0102f, 228.1f},   {3.1629f, 359.43f},  {3.2554f, 3222.12f},
    {2.9539f, 2144.49f}, {3.0368f, 2072.46f}, {2.6598f, 1357.42f},
    {4.0877f, 1406.65f}, {4.1275f, 1058.36f}, {9.7282f, 11498.73f},
    {8.5322f, 3361.33f}, {7.2344f, 2095.91f}, {5.3605f, 1049.31f},
    {3.718f, 966.27f},   {3.6408f, 1571.36f}, {3.4961f, 1183.59f},
    {3.5108f, 787.76f},  {3.0537f, 563.93f},  {3.0261f, 592.91f},
    {3.1735f, 430.82f},  {3.1773f, 812.57f},  {3.8357f, 4533.53f},
    {3.1109f, 3440.92f}, {3.2122f, 3859.82f}, {2.8263f, 2729.6f},
    {2.412f, 1864.19f},  {1.894f, 1175.73f},  {11.2061f, 32141.18f},
    {6.821f, 27655.14f}, {7.2367f, 2864.2f},  {3.901f, 3563.45f},
    {4.0857f, 3266.43f}, {4.045f, 3967.23f},  {3.4813f, 2233.82f},
    {3.0487f, 1393.49f}, {2.7795f, 1315.09f}, {2.8673f, 1311.47f},
    {3.3339f, 1460.56f}, {3.0086f, 1662.99f}, {3.9919f, 8089.97f},
    {3.4209f, 6887.05f}, {3.5649f, 8799.32f}, {3.0288f, 6136.5f},
    {2.262f, 3757.31f},  {1.3837f, 2561.18f}, {12.171f, 66580.83f},
    {0.f,0.f},{0.f,0.f},{0.f,0.f},{0.f,0.f},{0.f,0.f},{0.f,0.f},{0.f,0.f},
    {0.f,0.f},{0.f,0.f},{0.f,0.f},{0.f,0.f},{0.f,0.f},{0.f,0.f},{0.f,0.f},
    {6.0791f, 27593.76f}, {5.7661f, 15364.65f}, {3.6366f, 2734.5f},
    {4.241f, 4801.82f},   {4.1348f, 5685.94f},  {3.4213f, 2786.0f},
    {3.2486f, 2699.79f},  {2.9588f, 2282.6f},   {2.9381f, 2476.79f},
    {2.7711f, 2988.7f},   {2.5816f, 2506.63f},  {3.785f, 8916.84f},
    {3.5381f, 8694.22f},  {3.6985f, 11821.61f}, {3.0551f, 8410.64f},
};

__device__ __forceinline__ float gnb_energy_eval(float2 ps, float2 pr, float rlen) {
    float env;
    if (rlen < 8.0f) {
        env = 1.0f;
    } else {
        float x = (rlen - 8.0f) * 0.5f;          // records guarantee x < 1
        float x2 = x * x;
        float x6 = x2 * x2 * x2;
        env = 1.0f - 28.0f * x6 + 48.0f * x6 * x - 21.0f * x6 * x2;
    }
    float sR  = ps.y * pr.y;                     // sqrt(R_ij)
    float C6  = ps.x * pr.x;                     // sqrt(C6_s*C6_r)
    float Rij = sR * sR;
    float R3  = Rij * Rij * Rij;
    float R6  = R3 * R3;
    float r0  = 0.4f * sR + 4.0f;
    float t   = r0 / rlen;
    float t2 = t * t, t4 = t2 * t2, t8 = t4 * t4;
    float t14 = t8 * t4 * t2;
    float fd = 1.0f / (1.0f + 6.0f * t14);
    float rl2 = rlen * rlen;
    float r6 = rl2 * rl2 * rl2;
    return -0.5f * C6 / (R6 + r6) * fd * env;
}

// LDS plan (byte offsets into smem, 16B-aligned base):
//   scatter view: cnt u32[132] @0 .. gbase u32[128] @528 .. srec uint2[4096] @1056
//                 .. bmap u8[4096] @33824  (total 37920 B)
//   energy view:  acc f32[2*(1024+8)] @0 .. p2loc f32x2[1024] @8256
//                 .. ptab f32x2[96] @16448 (total 17216 B)
#define SMEM_BYTES 37952

__global__ void __launch_bounds__(SBLK, 8)
gnb_mega(const int* __restrict__ send, const int* __restrict__ recv,
         const float* __restrict__ len, const int* __restrict__ Z,
         float* __restrict__ out,
         unsigned* __restrict__ cursor, unsigned* __restrict__ ocur,
         int* __restrict__ cn, float* __restrict__ ovf,
         float2* __restrict__ PT, unsigned* __restrict__ isCN,
         unsigned char* __restrict__ pid, float* __restrict__ rep,
         uint4* __restrict__ ovrec, uint2* __restrict__ buckets,
         int n_nodes, int n_edges, int NB2, int nw,
         int cap, unsigned ocap, int zwords, int ntiles,
         int phase_lo, int phase_hi) {
    __shared__ __align__(16) char smem[SMEM_BYTES];
    unsigned*      s_cnt   = (unsigned*)smem;                  // [MAXB+1]
    unsigned*      s_gbase = (unsigned*)(smem + 528);          // [MAXB]
    uint2*         s_srec  = (uint2*)(smem + 1056);            // [TILE]
    unsigned char* s_bmap  = (unsigned char*)(smem + 33824);   // [TILE]
    float*         e_acc   = (float*)smem;                     // [2][B2SIZE+8]
    float2*        e_p2    = (float2*)(smem + 8256);           // [B2SIZE]
    float2*        e_ptab  = (float2*)(smem + 16448);          // [96]

    cg::grid_group grid = cg::this_grid();
    const int tid  = threadIdx.x;
    const int gtid = blockIdx.x * SBLK + tid;
    const int gstr = gridDim.x * SBLK;

    for (int phase = phase_lo; phase <= phase_hi; ++phase) {
        if (phase == 0) {
            // ---- init: zero cursor/ocur/cn/ovf, build isCN bitmask + PT table
            int* zp = (int*)cursor;                 // ws base
            for (int i = gtid; i < zwords; i += gstr) zp[i] = 0;
            for (int w = gtid; w < nw; w += gstr) {
                unsigned m = 0;
                int base = w << 5;
                int lim = n_nodes - base; if (lim > 32) lim = 32;
                for (int k = 0; k < lim; ++k) {
                    int z = Z[base + k];
                    if (z == 6 || z == 7) m |= (1u << k);
                }
                isCN[w] = m;
            }
            if (gtid < 91) {
                float R, C6;
                if      (gtid < 87)  { float2 rc = GNB_RC6[gtid]; R = rc.x; C6 = rc.y; }
                else if (gtid == 87) { R = 2.2348f; C6 = 429.69f; }   // C sp2
                else if (gtid == 88) { R = 1.8219f; C6 = 184.28f; }   // C sp3
                else if (gtid == 89) { R = 2.6454f; C6 = 720.18f; }   // N cn<=2
                else                 { R = 2.4667f; C6 = 482.54f; }   // N cn>=3
                PT[gtid] = make_float2(sqrtf(C6), sqrtf(sqrtf(R)));
            }
        } else if (phase == 1) {
            // ---- scatter: round-7 reload structure, tile loop
            for (int t = blockIdx.x; t < ntiles; t += gridDim.x) {
                for (int b = tid; b < MAXB + 1; b += SBLK) s_cnt[b] = 0;
                __syncthreads();
                const int e0 = t * TILE;

                // pass 1: histogram kept (len<10) + fused filtered degree (all)
                #pragma unroll
                for (int k = 0; k < 2; ++k) {
                    int base = e0 + (k * SBLK + tid) * 4;
                    if (base + 3 < n_edges) {
                        int4   rr = *(const int4*)(recv + base);
                        float4 ll = *(const float4*)(len + base);
                        int rv[4] = {rr.x, rr.y, rr.z, rr.w};
                        float lv[4] = {ll.x, ll.y, ll.z, ll.w};
                        #pragma unroll
                        for (int j = 0; j < 4; ++j) {
                            unsigned r = (unsigned)rv[j];
                            if ((isCN[r >> 5] >> (r & 31)) & 1u) atomicAdd(&cn[r], 1);
                            if (lv[j] < 10.0f) atomicAdd(&s_cnt[r >> B2SHIFT], 1u);
                        }
                    } else {
                        int lim = n_edges - base; if (lim < 0) lim = 0; if (lim > 4) lim = 4;
                        for (int j = 0; j < lim; ++j) {
                            unsigned r = (unsigned)recv[base + j];
                            if ((isCN[r >> 5] >> (r & 31)) & 1u) atomicAdd(&cn[r], 1);
                            if (len[base + j] < 10.0f) atomicAdd(&s_cnt[r >> B2SHIFT], 1u);
                        }
                    }
                }
                __syncthreads();

                if (tid < NB2) s_gbase[tid] = atomicAdd(&cursor[tid], s_cnt[tid]);
                __syncthreads();
                if (tid == 0) {                   // in-place exclusive scan
                    unsigned acc = 0;
                    for (int b = 0; b < NB2; ++b) {
                        unsigned c = s_cnt[b];
                        s_cnt[b] = acc;           // startp -> pass-2 cursor
                        s_gbase[b] -= acc;        // g = gbase[b] + slot
                        acc += c;
                    }
                    s_cnt[NB2] = acc;             // total kept
                }
                __syncthreads();

                // pass 2: reload tile (L2-warm), place records bucket-sorted
                #pragma unroll
                for (int k = 0; k < 2; ++k) {
                    int base = e0 + (k * SBLK + tid) * 4;
                    if (base + 3 < n_edges) {
                        int4   sv = *(const int4*)(send + base);
                        int4   rr = *(const int4*)(recv + base);
                        uint4  ll = *(const uint4*)(len + base);
                        int ss[4] = {sv.x, sv.y, sv.z, sv.w};
                        int rv[4] = {rr.x, rr.y, rr.z, rr.w};
                        unsigned lv[4] = {ll.x, ll.y, ll.z, ll.w};
                        #pragma unroll
                        for (int j = 0; j < 4; ++j) {
                            if (__uint_as_float(lv[j]) >= 10.0f) continue;
                            unsigned r = (unsigned)rv[j];
                            unsigned b = r >> B2SHIFT;
                            unsigned slot = atomicAdd(&s_cnt[b], 1u);
                            s_srec[slot] = make_uint2((unsigned)ss[j] | ((r & (B2SIZE - 1)) << 17),
                                                      lv[j]);
                            s_bmap[slot] = (unsigned char)b;
                        }
                    } else {
                        int lim = n_edges - base; if (lim < 0) lim = 0; if (lim > 4) lim = 4;
                        for (int j = 0; j < lim; ++j) {
                            unsigned lbits = ((const unsigned*)len)[base + j];
                            if (__uint_as_float(lbits) >= 10.0f) continue;
                            unsigned r = (unsigned)recv[base + j];
                            unsigned b = r >> B2SHIFT;
                            unsigned slot = atomicAdd(&s_cnt[b], 1u);
                            s_srec[slot] = make_uint2((unsigned)send[base + j] |
                                                      ((r & (B2SIZE - 1)) << 17), lbits);
                            s_bmap[slot] = (unsigned char)b;
                        }
                    }
                }
                __syncthreads();

                // phase C: coalesced copy of bucket runs
                unsigned total = s_cnt[NB2];
                for (unsigned i = tid; i < total; i += SBLK) {
                    unsigned b = s_bmap[i];
                    unsigned g = s_gbase[b] + i;
                    uint2 rec = s_srec[i];
                    if (g < (unsigned)cap) {
                        buckets[(size_t)b * cap + g] = rec;
                    } else {
                        unsigned o = atomicAdd(ocur, 1u);
                        unsigned r = ((unsigned)b << B2SHIFT) | ((rec.x >> 17) & (B2SIZE - 1));
                        if (o < ocap) ovrec[o] = make_uint4(r, rec.x & 0x1FFFFu, rec.y, 0u);
                    }
                }
                // next iteration's cnt-zero + barrier provides WAR safety
            }
        } else if (phase == 2) {
            // ---- params: cn-resolved class id per node
            for (int i = gtid; i < n_nodes; i += gstr) {
                int z = Z[i];
                int id = z;
                if (z == 6)      id = (cn[i] <= 3) ? 87 : 88;
                else if (z == 7) id = (cn[i] <= 2) ? 89 : 90;
                pid[i] = (unsigned char)id;
            }
        } else if (phase == 3) {
            // ---- energy: (bin,slice) items + OVB overflow items
            const int nmain = NB2 * ES;
            for (int item = blockIdx.x; item < nmain + OVB; item += gridDim.x) {
                if (item >= nmain) {              // overflow chunk (rare path)
                    unsigned n = *ocur; if (n > ocap) n = ocap;
                    for (unsigned i = (unsigned)(item - nmain) * SBLK + tid; i < n;
                         i += OVB * SBLK) {
                        uint4 rec = ovrec[i];
                        float rlen = __uint_as_float(rec.z);
                        if (rlen >= 10.0f) continue;
                        float e = gnb_energy_eval(PT[pid[rec.y]], PT[pid[rec.x]], rlen);
                        atomicAdd(&ovf[rec.x], e);
                    }
                    continue;
                }
                const int b  = item / ES;
                const int sl = item % ES;
                if (tid < 91) e_ptab[tid] = PT[tid];
                for (int i = tid; i < 2 * (B2SIZE + 8); i += SBLK) e_acc[i] = 0.0f;
                for (int i = tid; i < B2SIZE; i += SBLK) {
                    int node = (b << B2SHIFT) + i;
                    e_p2[i] = (node < n_nodes) ? PT[pid[node]] : make_float2(0.f, 0.f);
                }
                __syncthreads();

                unsigned count = cursor[b];
                if (count > (unsigned)cap) count = (unsigned)cap;
                unsigned seg = (count + ES - 1) / ES;
                unsigned st  = (unsigned)sl * seg;
                unsigned en  = st + seg; if (en > count) en = count;
                const uint2* src = buckets + (size_t)b * cap;
                const int rr = (tid >> 6) & 1;
                for (unsigned i = st + tid; i < en; i += SBLK) {
                    uint2 rec = src[i];
                    unsigned s  = rec.x & 0x1FFFFu;
                    unsigned rl = (rec.x >> 17) & (B2SIZE - 1);
                    float e = gnb_energy_eval(e_ptab[pid[s]], e_p2[rl],
                                              __uint_as_float(rec.y));
                    atomicAdd(&e_acc[rr * (B2SIZE + 8) + rl], e);
                }
                __syncthreads();

                float* dst = rep + (size_t)item * B2SIZE;
                for (int i = tid; i < B2SIZE; i += SBLK)
                    dst[i] = e_acc[i] + e_acc[B2SIZE + 8 + i];
                __syncthreads();                  // protect acc/p2 from next item
            }
        } else {
            // ---- reduce
            for (int i = gtid; i < n_nodes; i += gstr) {
                int b = i >> B2SHIFT;
                int j = i & (B2SIZE - 1);
                const float* src = rep + ((size_t)b * ES) * B2SIZE + j;
                float sum = ovf[i];
                #pragma unroll
                for (int s = 0; s < ES; ++s) sum += src[(size_t)s * B2SIZE];
                out[i] = sum;
            }
        }
        if (phase < phase_hi) grid.sync();
    }
}

extern "C" void kernel_launch(void* const* d_in, const int* in_sizes, int n_in,
                              void* d_out, int out_size, void* d_ws, size_t ws_size,
                              hipStream_t stream) {
    const int*   Z    = (const int*)d_in[0];
    const int*   eidx = (const int*)d_in[1];
    const float* lenp = (const float*)d_in[2];
    float*       out  = (float*)d_out;

    int n_nodes = in_sizes[0];
    int n_edges = in_sizes[2];
    const int* send = eidx;
    const int* recv = eidx + n_edges;

    int NB2 = (n_nodes + B2SIZE - 1) >> B2SHIFT;       // 98 for n=100000
    int nw  = (n_nodes + 31) >> 5;
    size_t nwp   = ((size_t)nw + 3) & ~3ull;
    size_t npidw = (((size_t)n_nodes + 3) / 4 + 3) & ~3ull;

    // ws layout (words): cursor 128 | ocur 8 | cn n | ovf n | PT 192 | isCN | pid | rep | tail
    size_t o_cn   = 136;
    size_t o_ovf  = o_cn + n_nodes;
    size_t o_PT   = o_ovf + n_nodes;
    size_t o_isCN = o_PT + 192;
    size_t o_pid  = o_isCN + nwp;
    size_t o_rep  = (o_pid + npidw + 3) & ~3ull;
    size_t rep_w  = (size_t)NB2 * ES * B2SIZE;
    size_t o_tail = (o_rep + rep_w + 3) & ~3ull;

    char* ws = (char*)d_ws;
    unsigned*      cursor = (unsigned*)ws;
    unsigned*      ocur   = (unsigned*)(ws + 128 * 4);
    int*           cn     = (int*)(ws + o_cn * 4);
    float*         ovf    = (float*)(ws + o_ovf * 4);
    float2*        PT     = (float2*)(ws + o_PT * 4);
    unsigned*      isCN   = (unsigned*)(ws + o_isCN * 4);
    unsigned char* pid    = (unsigned char*)(ws + o_pid * 4);
    float*         rep    = (float*)(ws + o_rep * 4);

    size_t total_words = ws_size / 4;
    size_t avail = total_words > o_tail ? total_words - o_tail : 0;
    size_t ovw = avail / 32;
    unsigned ocap = (unsigned)(ovw / 4);
    long cap = (long)((avail - ovw) / (2 * (size_t)NB2));
    if (cap > n_edges) cap = n_edges;
    if (cap < 0) cap = 0;
    uint4* ovrec   = (uint4*)(ws + o_tail * 4);
    uint2* buckets = (uint2*)(ws + (o_tail + (size_t)ocap * 4) * 4);

    int zwords = (int)o_PT;                       // cursor+ocur+cn+ovf
    int ntiles = (n_edges + TILE - 1) / TILE;
    int capi   = (int)cap;

    // Grid: co-resident blocks only. LDS 37.9KB -> 4 blocks/CU; VGPR capped by
    // __launch_bounds__(512,8). Verify via occupancy API, clamp [1,4].
    int dev = 0; hipGetDevice(&dev);
    int cus = 256;
    hipDeviceGetAttribute(&cus, hipDeviceAttributeMultiprocessorCount, dev);
    int occ = 0;
    if (hipOccupancyMaxActiveBlocksPerMultiprocessor(&occ, gnb_mega, SBLK, 0)
        != hipSuccess || occ < 1) occ = 4;
    if (occ > 4) occ = 4;
    int grid = occ * cus;

    int plo = 0, phi = 4;
    void* args[] = {
        (void*)&send, (void*)&recv, (void*)&lenp, (void*)&Z, (void*)&out,
        (void*)&cursor, (void*)&ocur, (void*)&cn, (void*)&ovf,
        (void*)&PT, (void*)&isCN, (void*)&pid, (void*)&rep,
        (void*)&ovrec, (void*)&buckets,
        (void*)&n_nodes, (void*)&n_edges, (void*)&NB2, (void*)&nw,
        (void*)&capi, (void*)&ocap, (void*)&zwords, (void*)&ntiles,
        (void*)&plo, (void*)&phi,
    };
    hipError_t err = hipLaunchCooperativeKernel((void*)gnb_mega, dim3(grid), dim3(SBLK),
                                                args, 0, stream);
    if (err != hipSuccess) {
        (void)hipGetLastError();                  // clear sticky error
        // Fallback: phase-by-phase normal launches (no grid.sync executed).
        int node_blocks = (n_nodes + SBLK - 1) / SBLK;
        int pg[5] = { grid, ntiles, node_blocks, NB2 * ES + OVB, node_blocks };
        for (int p = 0; p < 5; ++p) {
            gnb_mega<<<pg[p], SBLK, 0, stream>>>(
                send, recv, lenp, Z, out, cursor, ocur, cn, ovf, PT, isCN, pid,
                rep, ovrec, buckets, n_nodes, n_edges, NB2, nw, capi, ocap,
                zwords, ntiles, p, p);
        }
    }
}

// Round 10
// 396.238 us; speedup vs baseline: 1.2034x; 1.2034x over previous
//
#include <hip/hip_runtime.h>

// GNB dispersion — Round 10: 4 dispatches.
//   init (zero ctl/cn + isCN bitmask + PT table)
//   scatter (round-7 verbatim: histogram+degree / scan / sort-in-LDS / coalesced
//            bucket stores; 512 thr, TILE 4096, no reg-held tile)
//   params (pid class per node)
//   energy (per (bin,slice) LDS accumulate + pid gather; LAST block of each bin
//           reduces all slices + scans ovf queue + writes out — no reduce kernel)
// Record: uint2{ x = s | (r&1023)<<17, y = len bits }; bucket id = r>>10.
// Assumes n_nodes <= 131072 (17-bit ids), NB2 <= 128.

#define B2SHIFT 10
#define B2SIZE  1024
#define TILE    4096
#define SBLK    512
#define ES      16
#define MAXB    128

__device__ __constant__ float2 GNB_RC6[87] = {
    {0.f, 0.f},
    {3.6516f, 95.99f},   {2.1843f, 40.67f},   {1.2711f, 70.21f},
    {3.3497f, 114.51f},  {2.7079f, 152.36f},  {1.8219f, 184.28f},
    {2.4667f, 482.54f},  {2.365f, 405.57f},   {1.5062f, 218.45f},
    {1.8233f, 174.81f},  {1.3974f, 181.7f},   {3.3515f, 263.02f},
    {3.0102f, 228.1f},   {3.1629f, 359.43f},  {3.2554f, 3222.12f},
    {2.9539f, 2144.49f}, {3.0368f, 2072.46f}, {2.6598f, 1357.42f},
    {4.0877f, 1406.65f}, {4.1275f, 1058.36f}, {9.7282f, 11498.73f},
    {8.5322f, 3361.33f}, {7.2344f, 2095.91f}, {5.3605f, 1049.31f},
    {3.718f, 966.27f},   {3.6408f, 1571.36f}, {3.4961f, 1183.59f},
    {3.5108f, 787.76f},  {3.0537f, 563.93f},  {3.0261f, 592.91f},
    {3.1735f, 430.82f},  {3.1773f, 812.57f},  {3.8357f, 4533.53f},
    {3.1109f, 3440.92f}, {3.2122f, 3859.82f}, {2.8263f, 2729.6f},
    {2.412f, 1864.19f},  {1.894f, 1175.73f},  {11.2061f, 32141.18f},
    {6.821f, 27655.14f}, {7.2367f, 2864.2f},  {3.901f, 3563.45f},
    {4.0857f, 3266.43f}, {4.045f, 3967.23f},  {3.4813f, 2233.82f},
    {3.0487f, 1393.49f}, {2.7795f, 1315.09f}, {2.8673f, 1311.47f},
    {3.3339f, 1460.56f}, {3.0086f, 1662.99f}, {3.9919f, 8089.97f},
    {3.4209f, 6887.05f}, {3.5649f, 8799.32f}, {3.0288f, 6136.5f},
    {2.262f, 3757.31f},  {1.3837f, 2561.18f}, {12.171f, 66580.83f},
    {0.f,0.f},{0.f,0.f},{0.f,0.f},{0.f,0.f},{0.f,0.f},{0.f,0.f},{0.f,0.f},
    {0.f,0.f},{0.f,0.f},{0.f,0.f},{0.f,0.f},{0.f,0.f},{0.f,0.f},{0.f,0.f},
    {6.0791f, 27593.76f}, {5.7661f, 15364.65f}, {3.6366f, 2734.5f},
    {4.241f, 4801.82f},   {4.1348f, 5685.94f},  {3.4213f, 2786.0f},
    {3.2486f, 2699.79f},  {2.9588f, 2282.6f},   {2.9381f, 2476.79f},
    {2.7711f, 2988.7f},   {2.5816f, 2506.63f},  {3.785f, 8916.84f},
    {3.5381f, 8694.22f},  {3.6985f, 11821.61f}, {3.0551f, 8410.64f},
};

// Zero scratch (cursor+ocur+done+cn), build isCN bitmask + PT table.
// PT[id] = {sqrt(C6), R^(1/4)}; ids 87/88 = C sp2/sp3, 89/90 = N cn<=2/cn>=3.
__global__ void gnb_init(const int* __restrict__ Z, unsigned* __restrict__ isCN,
                         float2* __restrict__ PT, int nw, int n_nodes,
                         int* __restrict__ zp, int zwords) {
    int stride = gridDim.x * blockDim.x;
    int t0 = blockIdx.x * blockDim.x + threadIdx.x;
    for (int i = t0; i < zwords; i += stride) zp[i] = 0;
    for (int w = t0; w < nw; w += stride) {
        unsigned m = 0;
        int base = w << 5;
        int lim = n_nodes - base; if (lim > 32) lim = 32;
        for (int k = 0; k < lim; ++k) {
            int z = Z[base + k];
            if (z == 6 || z == 7) m |= (1u << k);
        }
        isCN[w] = m;
    }
    if (t0 < 91) {
        float R, C6;
        if      (t0 < 87)  { float2 rc = GNB_RC6[t0]; R = rc.x; C6 = rc.y; }
        else if (t0 == 87) { R = 2.2348f; C6 = 429.69f; }   // C sp2
        else if (t0 == 88) { R = 1.8219f; C6 = 184.28f; }   // C sp3
        else if (t0 == 89) { R = 2.6454f; C6 = 720.18f; }   // N cn<=2
        else               { R = 2.4667f; C6 = 482.54f; }   // N cn>=3
        PT[t0] = make_float2(sqrtf(C6), sqrtf(sqrtf(R)));
    }
}

// Round-7 scatter, verbatim: pass1 histogram (kept, len<10) + fused filtered
// degree (all edges); scan + cursor bump; pass2 reload tile, sort in LDS;
// phase C coalesced bucket-run copy. 512 thr, 39.4KB LDS.
__global__ void __launch_bounds__(SBLK)
gnb_scatter(const int* __restrict__ send, const int* __restrict__ recv,
            const float* __restrict__ len, const unsigned* __restrict__ isCN,
            int* __restrict__ cn,
            uint2* __restrict__ buckets, unsigned* __restrict__ cursor,
            uint4* __restrict__ ovrec, unsigned* __restrict__ ocur,
            int n_edges, int cap, unsigned ocap, int NB2) {
    __shared__ unsigned cnt[MAXB];
    __shared__ unsigned pos[MAXB];
    __shared__ unsigned startp[MAXB + 1];
    __shared__ unsigned gbase[MAXB];
    __shared__ uint2 srec[TILE];
    __shared__ unsigned char bmap[TILE];
    const int tid = threadIdx.x;
    const int e0  = blockIdx.x * TILE;

    for (int b = tid; b < MAXB; b += SBLK) { cnt[b] = 0; pos[b] = 0; }
    __syncthreads();

    #pragma unroll
    for (int k = 0; k < 2; ++k) {
        int base = e0 + (k * SBLK + tid) * 4;
        if (base + 3 < n_edges) {
            int4   rv = *(const int4*)(recv + base);
            float4 lv = *(const float4*)(len + base);
            int rr[4] = {rv.x, rv.y, rv.z, rv.w};
            float ll[4] = {lv.x, lv.y, lv.z, lv.w};
            #pragma unroll
            for (int j = 0; j < 4; ++j) {
                unsigned r = (unsigned)rr[j];
                if (ll[j] < 10.0f) atomicAdd(&cnt[r >> B2SHIFT], 1u);
                if ((isCN[r >> 5] >> (r & 31)) & 1u) atomicAdd(&cn[r], 1);
            }
        } else {
            int lim = n_edges - base; if (lim < 0) lim = 0; if (lim > 4) lim = 4;
            for (int j = 0; j < lim; ++j) {
                unsigned r = (unsigned)recv[base + j];
                if (len[base + j] < 10.0f) atomicAdd(&cnt[r >> B2SHIFT], 1u);
                if ((isCN[r >> 5] >> (r & 31)) & 1u) atomicAdd(&cn[r], 1);
            }
        }
    }
    __syncthreads();

    if (tid == 0) {
        unsigned acc = 0;
        for (int b = 0; b < NB2; ++b) { startp[b] = acc; acc += cnt[b]; }
        startp[NB2] = acc;
    }
    __syncthreads();
    if (tid < NB2) gbase[tid] = atomicAdd(&cursor[tid], cnt[tid]);
    __syncthreads();

    #pragma unroll
    for (int k = 0; k < 2; ++k) {
        int base = e0 + (k * SBLK + tid) * 4;
        if (base + 3 < n_edges) {
            int4   sv = *(const int4*)(send + base);
            int4   rv = *(const int4*)(recv + base);
            uint4  lv = *(const uint4*)(len + base);
            int ss[4] = {sv.x, sv.y, sv.z, sv.w};
            int rr[4] = {rv.x, rv.y, rv.z, rv.w};
            unsigned ll[4] = {lv.x, lv.y, lv.z, lv.w};
            #pragma unroll
            for (int j = 0; j < 4; ++j) {
                if (__uint_as_float(ll[j]) >= 10.0f) continue;
                unsigned r = (unsigned)rr[j];
                unsigned b = r >> B2SHIFT;
                unsigned slot = startp[b] + atomicAdd(&pos[b], 1u);
                srec[slot] = make_uint2((unsigned)ss[j] | ((r & (B2SIZE - 1)) << 17), ll[j]);
                bmap[slot] = (unsigned char)b;
            }
        } else {
            int lim = n_edges - base; if (lim < 0) lim = 0; if (lim > 4) lim = 4;
            for (int j = 0; j < lim; ++j) {
                unsigned lbits = ((const unsigned*)len)[base + j];
                if (__uint_as_float(lbits) >= 10.0f) continue;
                unsigned r = (unsigned)recv[base + j];
                unsigned b = r >> B2SHIFT;
                unsigned slot = startp[b] + atomicAdd(&pos[b], 1u);
                srec[slot] = make_uint2((unsigned)send[base + j] | ((r & (B2SIZE - 1)) << 17),
                                        lbits);
                bmap[slot] = (unsigned char)b;
            }
        }
    }
    __syncthreads();

    unsigned total = startp[NB2];
    for (unsigned i = tid; i < total; i += SBLK) {
        unsigned b = bmap[i];
        unsigned g = gbase[b] + (i - startp[b]);
        uint2 rec = srec[i];
        if (g < (unsigned)cap) {
            buckets[(size_t)b * cap + g] = rec;
        } else {
            unsigned o = atomicAdd(ocur, 1u);
            unsigned r = ((unsigned)b << B2SHIFT) | ((rec.x >> 17) & (B2SIZE - 1));
            if (o < ocap) ovrec[o] = make_uint4(r, rec.x & 0x1FFFFu, rec.y, 0u);
        }
    }
}

// cn-resolved parameter class id per node (1 byte).
__global__ void gnb_params(const int* __restrict__ Z, const int* __restrict__ cn,
                           unsigned char* __restrict__ pid, int n_nodes) {
    int i = blockIdx.x * blockDim.x + threadIdx.x;
    if (i >= n_nodes) return;
    int z = Z[i];
    int id = z;
    if (z == 6)      id = (cn[i] <= 3) ? 87 : 88;
    else if (z == 7) id = (cn[i] <= 2) ? 89 : 90;
    pid[i] = (unsigned char)id;
}

__device__ __forceinline__ float gnb_energy_eval(float2 ps, float2 pr, float rlen) {
    float env;
    if (rlen < 8.0f) {
        env = 1.0f;
    } else {
        float x = (rlen - 8.0f) * 0.5f;          // records guarantee x < 1
        float x2 = x * x;
        float x6 = x2 * x2 * x2;
        env = 1.0f - 28.0f * x6 + 48.0f * x6 * x - 21.0f * x6 * x2;
    }
    float sR  = ps.y * pr.y;                     // sqrt(R_ij)
    float C6  = ps.x * pr.x;                     // sqrt(C6_s*C6_r)
    float Rij = sR * sR;
    float R3  = Rij * Rij * Rij;
    float R6  = R3 * R3;
    float r0  = 0.4f * sR + 4.0f;
    float t   = r0 / rlen;
    float t2 = t * t, t4 = t2 * t2, t8 = t4 * t4;
    float t14 = t8 * t4 * t2;
    float fd = 1.0f / (1.0f + 6.0f * t14);
    float rl2 = rlen * rlen;
    float r6 = rl2 * rl2 * rl2;
    return -0.5f * C6 / (R6 + r6) * fd * env;
}

// Per (bin,slice): accumulate slice records into LDS; write rep slice; the LAST
// finishing block of each bin sums all slices + scans the overflow queue for its
// bin + writes out directly (reduce kernel fused away).
__global__ void __launch_bounds__(256)
gnb_energy(const uint2* __restrict__ buckets, const unsigned* __restrict__ cursor,
           const float2* __restrict__ PT, const unsigned char* __restrict__ pid,
           float* __restrict__ rep, unsigned* __restrict__ done,
           const uint4* __restrict__ ovrec, const unsigned* __restrict__ ocur,
           float* __restrict__ out, unsigned ocap, int cap, int n_nodes) {
    __shared__ float  acc[2][B2SIZE + 8];
    __shared__ float2 p2loc[B2SIZE];
    __shared__ float2 ptab[96];
    __shared__ unsigned s_old;
    const int tid = threadIdx.x;
    const int b   = blockIdx.x / ES;
    const int sl  = blockIdx.x % ES;
    const int rr  = (tid >> 6) & 1;

    if (tid < 91) ptab[tid] = PT[tid];
    for (int i = tid; i < 2 * (B2SIZE + 8); i += 256) acc[0][i] = 0.0f;
    for (int i = tid; i < B2SIZE; i += 256) {
        int node = (b << B2SHIFT) + i;
        p2loc[i] = (node < n_nodes) ? PT[pid[node]] : make_float2(0.f, 0.f);
    }
    __syncthreads();

    unsigned count = cursor[b];
    if (count > (unsigned)cap) count = (unsigned)cap;
    unsigned seg = (((count + ES - 1) / ES) + 1) & ~1u;      // even -> uint4 pairs
    unsigned st  = (unsigned)sl * seg;
    unsigned en  = st + seg; if (en > count) en = count;

    const uint2* src = buckets + (size_t)b * cap;
    for (unsigned i = st + 2 * tid; i < en; i += 512) {
        if (i + 1 < en) {
            uint4 q = *(const uint4*)(src + i);              // two records
            {
                unsigned s = q.x & 0x1FFFFu, rl = (q.x >> 17) & (B2SIZE - 1);
                float e = gnb_energy_eval(ptab[pid[s]], p2loc[rl], __uint_as_float(q.y));
                atomicAdd(&acc[rr][rl], e);
            }
            {
                unsigned s = q.z & 0x1FFFFu, rl = (q.z >> 17) & (B2SIZE - 1);
                float e = gnb_energy_eval(ptab[pid[s]], p2loc[rl], __uint_as_float(q.w));
                atomicAdd(&acc[rr][rl], e);
            }
        } else {
            uint2 rec = src[i];
            unsigned s = rec.x & 0x1FFFFu, rl = (rec.x >> 17) & (B2SIZE - 1);
            float e = gnb_energy_eval(ptab[pid[s]], p2loc[rl], __uint_as_float(rec.y));
            atomicAdd(&acc[rr][rl], e);
        }
    }
    __syncthreads();

    float* dst = rep + (size_t)blockIdx.x * B2SIZE;
    for (int i = tid; i < B2SIZE; i += 256) dst[i] = acc[0][i] + acc[1][i];

    // release our slice, then the last block of the bin reduces
    __threadfence();
    if (tid == 0) s_old = atomicAdd(&done[b], 1u);
    __syncthreads();
    if (s_old != ES - 1) return;
    __threadfence();                                          // acquire side

    // overflow records for this bin (queue normally empty) -> acc[0]
    {
        unsigned n = *ocur; if (n > ocap) n = ocap;
        for (unsigned i = tid; i < n; i += 256) {
            uint4 rec = ovrec[i];
            if ((int)(rec.x >> B2SHIFT) != b) continue;
            float rlen = __uint_as_float(rec.z);
            if (rlen >= 10.0f) continue;
            float e = gnb_energy_eval(ptab[pid[rec.y]], p2loc[rec.x & (B2SIZE - 1)], rlen);
            atomicAdd(&acc[0][rec.x & (B2SIZE - 1)], e);
        }
    }
    __syncthreads();

    const float* base = rep + ((size_t)b * ES) * B2SIZE;
    for (int i = tid; i < B2SIZE; i += 256) {
        int node = (b << B2SHIFT) + i;
        if (node >= n_nodes) continue;
        float sum = acc[0][i] - (acc[0][i] + acc[1][i]);      // keep only ovf part...
        // NOTE: acc[0] currently holds (our slice acc[0] half) + ovf adds; our full
        // slice is already in rep. Simply sum all ES slices + (acc-derived ovf).
        sum = 0.0f;
        #pragma unroll
        for (int s = 0; s < ES; ++s) sum += base[(size_t)s * B2SIZE + i];
        // ovf contribution = acc[0][i] + acc[1][i] - (our slice total already in rep)
        // Avoid double-count: recompute ovf-only by subtracting our slice value.
        sum += (acc[0][i] + acc[1][i]) - dst[i];
        out[node] = sum;
    }
}

extern "C" void kernel_launch(void* const* d_in, const int* in_sizes, int n_in,
                              void* d_out, int out_size, void* d_ws, size_t ws_size,
                              hipStream_t stream) {
    const int*   Z    = (const int*)d_in[0];
    const int*   eidx = (const int*)d_in[1];
    const float* len  = (const float*)d_in[2];
    float*       out  = (float*)d_out;

    const int n_nodes = in_sizes[0];
    const int n_edges = in_sizes[2];
    const int* send = eidx;
    const int* recv = eidx + n_edges;

    const int NB2 = (n_nodes + B2SIZE - 1) >> B2SHIFT;   // 98 for n=100000
    const int nw  = (n_nodes + 31) >> 5;
    const size_t nwp   = ((size_t)nw + 3) & ~3ull;
    const size_t npidw = (((size_t)n_nodes + 3) / 4 + 3) & ~3ull;

    // ws layout (words): cursor 128 | ocur 8 | done 128 | cn n | PT 192 | isCN | pid | rep | tail
    size_t o_done = 136;
    size_t o_cn   = 264;
    size_t o_PT   = o_cn + n_nodes;
    size_t o_isCN = o_PT + 192;
    size_t o_pid  = o_isCN + nwp;
    size_t o_rep  = (o_pid + npidw + 3) & ~3ull;
    size_t rep_w  = (size_t)NB2 * ES * B2SIZE;
    size_t o_tail = (o_rep + rep_w + 3) & ~3ull;

    char* ws = (char*)d_ws;
    unsigned*      cursor = (unsigned*)ws;
    unsigned*      ocur   = (unsigned*)(ws + 128 * 4);
    unsigned*      done   = (unsigned*)(ws + o_done * 4);
    int*           cn     = (int*)(ws + o_cn * 4);
    float2*        PT     = (float2*)(ws + o_PT * 4);
    unsigned*      isCN   = (unsigned*)(ws + o_isCN * 4);
    unsigned char* pid    = (unsigned char*)(ws + o_pid * 4);
    float*         rep    = (float*)(ws + o_rep * 4);

    size_t total_words = ws_size / 4;
    size_t avail = total_words > o_tail ? total_words - o_tail : 0;
    size_t ovw = avail / 32;
    unsigned ocap = (unsigned)(ovw / 4);
    long cap = (long)((avail - ovw) / (2 * (size_t)NB2));
    if (cap > n_edges) cap = n_edges;
    if (cap < 0) cap = 0;
    cap &= ~1L;                                   // even -> 16B-aligned record pairs
    uint4* ovrec   = (uint4*)(ws + o_tail * 4);
    uint2* buckets = (uint2*)(ws + (o_tail + (size_t)ocap * 4) * 4);

    const int B = 256;
    int node_blocks = (n_nodes + B - 1) / B;
    int scat_blocks = (n_edges + TILE - 1) / TILE;
    int zero_words  = (int)o_PT;                  // cursor+ocur+done+cn

    gnb_init<<<1024, B, 0, stream>>>(Z, isCN, PT, nw, n_nodes, (int*)ws, zero_words);
    gnb_scatter<<<scat_blocks, SBLK, 0, stream>>>(send, recv, len, isCN, cn, buckets,
                                                  cursor, ovrec, ocur, n_edges,
                                                  (int)cap, ocap, NB2);
    gnb_params<<<node_blocks, B, 0, stream>>>(Z, cn, pid, n_nodes);
    gnb_energy<<<NB2 * ES, B, 0, stream>>>(buckets, cursor, PT, pid, rep, done,
                                           ovrec, ocur, out, ocap, (int)cap, n_nodes);
}

// Round 11
// 204.475 us; speedup vs baseline: 2.3320x; 1.9378x over previous
//
#include <hip/hip_runtime.h>

// GNB dispersion — Round 11: best-known chain, no cross-workgroup sync anywhere.
//   init (zero ctl/cn + isCN bitmask + PT table)
//   scatter (round-7 structure + per-half duplicated cnt/pos histograms)
//   params (pid class per node)
//   energy (per (bin,slice) LDS accumulate, pid gather + LDS table, uint4 pairs;
//           tail blocks drain overflow queue)   [NO threadfence / done flags]
//   reduce (out = ovf + sum of slice replicas)
// Record: uint2{ x = s | (r&1023)<<17, y = len bits }; bucket id = r>>10.
// Assumes n_nodes <= 131072 (17-bit ids), NB2 <= 128.

#define B2SHIFT 10
#define B2SIZE  1024
#define TILE    4096
#define SBLK    512
#define ES      16
#define MAXB    128
#define OVB     8

__device__ __constant__ float2 GNB_RC6[87] = {
    {0.f, 0.f},
    {3.6516f, 95.99f},   {2.1843f, 40.67f},   {1.2711f, 70.21f},
    {3.3497f, 114.51f},  {2.7079f, 152.36f},  {1.8219f, 184.28f},
    {2.4667f, 482.54f},  {2.365f, 405.57f},   {1.5062f, 218.45f},
    {1.8233f, 174.81f},  {1.3974f, 181.7f},   {3.3515f, 263.02f},
    {3.0102f, 228.1f},   {3.1629f, 359.43f},  {3.2554f, 3222.12f},
    {2.9539f, 2144.49f}, {3.0368f, 2072.46f}, {2.6598f, 1357.42f},
    {4.0877f, 1406.65f}, {4.1275f, 1058.36f}, {9.7282f, 11498.73f},
    {8.5322f, 3361.33f}, {7.2344f, 2095.91f}, {5.3605f, 1049.31f},
    {3.718f, 966.27f},   {3.6408f, 1571.36f}, {3.4961f, 1183.59f},
    {3.5108f, 787.76f},  {3.0537f, 563.93f},  {3.0261f, 592.91f},
    {3.1735f, 430.82f},  {3.1773f, 812.57f},  {3.8357f, 4533.53f},
    {3.1109f, 3440.92f}, {3.2122f, 3859.82f}, {2.8263f, 2729.6f},
    {2.412f, 1864.19f},  {1.894f, 1175.73f},  {11.2061f, 32141.18f},
    {6.821f, 27655.14f}, {7.2367f, 2864.2f},  {3.901f, 3563.45f},
    {4.0857f, 3266.43f}, {4.045f, 3967.23f},  {3.4813f, 2233.82f},
    {3.0487f, 1393.49f}, {2.7795f, 1315.09f}, {2.8673f, 1311.47f},
    {3.3339f, 1460.56f}, {3.0086f, 1662.99f}, {3.9919f, 8089.97f},
    {3.4209f, 6887.05f}, {3.5649f, 8799.32f}, {3.0288f, 6136.5f},
    {2.262f, 3757.31f},  {1.3837f, 2561.18f}, {12.171f, 66580.83f},
    {0.f,0.f},{0.f,0.f},{0.f,0.f},{0.f,0.f},{0.f,0.f},{0.f,0.f},{0.f,0.f},
    {0.f,0.f},{0.f,0.f},{0.f,0.f},{0.f,0.f},{0.f,0.f},{0.f,0.f},{0.f,0.f},
    {6.0791f, 27593.76f}, {5.7661f, 15364.65f}, {3.6366f, 2734.5f},
    {4.241f, 4801.82f},   {4.1348f, 5685.94f},  {3.4213f, 2786.0f},
    {3.2486f, 2699.79f},  {2.9588f, 2282.6f},   {2.9381f, 2476.79f},
    {2.7711f, 2988.7f},   {2.5816f, 2506.63f},  {3.785f, 8916.84f},
    {3.5381f, 8694.22f},  {3.6985f, 11821.61f}, {3.0551f, 8410.64f},
};

// Zero scratch (cursor+ocur+cn+ovf), build isCN bitmask + PT table.
// PT[id] = {sqrt(C6), R^(1/4)}; ids 87/88 = C sp2/sp3, 89/90 = N cn<=2/cn>=3.
__global__ void gnb_init(const int* __restrict__ Z, unsigned* __restrict__ isCN,
                         float2* __restrict__ PT, int nw, int n_nodes,
                         int* __restrict__ zp, int zwords) {
    int stride = gridDim.x * blockDim.x;
    int t0 = blockIdx.x * blockDim.x + threadIdx.x;
    for (int i = t0; i < zwords; i += stride) zp[i] = 0;
    for (int w = t0; w < nw; w += stride) {
        unsigned m = 0;
        int base = w << 5;
        int lim = n_nodes - base; if (lim > 32) lim = 32;
        for (int k = 0; k < lim; ++k) {
            int z = Z[base + k];
            if (z == 6 || z == 7) m |= (1u << k);
        }
        isCN[w] = m;
    }
    if (t0 < 91) {
        float R, C6;
        if      (t0 < 87)  { float2 rc = GNB_RC6[t0]; R = rc.x; C6 = rc.y; }
        else if (t0 == 87) { R = 2.2348f; C6 = 429.69f; }   // C sp2
        else if (t0 == 88) { R = 1.8219f; C6 = 184.28f; }   // C sp3
        else if (t0 == 89) { R = 2.6454f; C6 = 720.18f; }   // N cn<=2
        else               { R = 2.4667f; C6 = 482.54f; }   // N cn>=3
        PT[t0] = make_float2(sqrtf(C6), sqrtf(sqrtf(R)));
    }
}

// Round-7 scatter + per-half (waves 0-3 / 4-7) duplicated cnt/pos histograms.
// pass1: histogram kept (len<10) into cnt[half][b] + fused filtered degree;
// scan sums halves; pass2: reload tile, place records sorted-by-bucket in LDS
// (half-1 offset by half-0's count inside each bucket run); phase C: coalesced copy.
__global__ void __launch_bounds__(SBLK)
gnb_scatter(const int* __restrict__ send, const int* __restrict__ recv,
            const float* __restrict__ len, const unsigned* __restrict__ isCN,
            int* __restrict__ cn,
            uint2* __restrict__ buckets, unsigned* __restrict__ cursor,
            uint4* __restrict__ ovrec, unsigned* __restrict__ ocur,
            int n_edges, int cap, unsigned ocap, int NB2) {
    __shared__ unsigned cnt[2][MAXB];
    __shared__ unsigned pos[2][MAXB];
    __shared__ unsigned startp[MAXB + 1];   // bucket run start (both halves)
    __shared__ unsigned start1[MAXB];       // half-1 extra offset = cnt[0][b]
    __shared__ unsigned gbase[MAXB];
    __shared__ uint2 srec[TILE];
    __shared__ unsigned char bmap[TILE];
    const int tid  = threadIdx.x;
    const int half = tid >> 8;              // 0: waves 0-3, 1: waves 4-7
    const int e0   = blockIdx.x * TILE;

    for (int b = tid; b < 2 * MAXB; b += SBLK) {
        cnt[0][b] = 0;                      // flattened: covers cnt[0..1][...]
        pos[0][b] = 0;
    }
    __syncthreads();

    #pragma unroll
    for (int k = 0; k < 2; ++k) {
        int base = e0 + (k * SBLK + tid) * 4;
        if (base + 3 < n_edges) {
            int4   rv = *(const int4*)(recv + base);
            float4 lv = *(const float4*)(len + base);
            int rr[4] = {rv.x, rv.y, rv.z, rv.w};
            float ll[4] = {lv.x, lv.y, lv.z, lv.w};
            #pragma unroll
            for (int j = 0; j < 4; ++j) {
                unsigned r = (unsigned)rr[j];
                if (ll[j] < 10.0f) atomicAdd(&cnt[half][r >> B2SHIFT], 1u);
                if ((isCN[r >> 5] >> (r & 31)) & 1u) atomicAdd(&cn[r], 1);
            }
        } else {
            int lim = n_edges - base; if (lim < 0) lim = 0; if (lim > 4) lim = 4;
            for (int j = 0; j < lim; ++j) {
                unsigned r = (unsigned)recv[base + j];
                if (len[base + j] < 10.0f) atomicAdd(&cnt[half][r >> B2SHIFT], 1u);
                if ((isCN[r >> 5] >> (r & 31)) & 1u) atomicAdd(&cn[r], 1);
            }
        }
    }
    __syncthreads();

    if (tid == 0) {
        unsigned acc = 0;
        for (int b = 0; b < NB2; ++b) {
            startp[b] = acc;
            start1[b] = cnt[0][b];          // half-1 starts after half-0's records
            acc += cnt[0][b] + cnt[1][b];
        }
        startp[NB2] = acc;
    }
    __syncthreads();
    if (tid < NB2) gbase[tid] = atomicAdd(&cursor[tid], cnt[0][tid] + cnt[1][tid]);
    __syncthreads();

    #pragma unroll
    for (int k = 0; k < 2; ++k) {
        int base = e0 + (k * SBLK + tid) * 4;
        if (base + 3 < n_edges) {
            int4   sv = *(const int4*)(send + base);
            int4   rv = *(const int4*)(recv + base);
            uint4  lv = *(const uint4*)(len + base);
            int ss[4] = {sv.x, sv.y, sv.z, sv.w};
            int rr[4] = {rv.x, rv.y, rv.z, rv.w};
            unsigned ll[4] = {lv.x, lv.y, lv.z, lv.w};
            #pragma unroll
            for (int j = 0; j < 4; ++j) {
                if (__uint_as_float(ll[j]) >= 10.0f) continue;
                unsigned r = (unsigned)rr[j];
                unsigned b = r >> B2SHIFT;
                unsigned slot = startp[b] + (half ? start1[b] : 0u)
                              + atomicAdd(&pos[half][b], 1u);
                srec[slot] = make_uint2((unsigned)ss[j] | ((r & (B2SIZE - 1)) << 17), ll[j]);
                bmap[slot] = (unsigned char)b;
            }
        } else {
            int lim = n_edges - base; if (lim < 0) lim = 0; if (lim > 4) lim = 4;
            for (int j = 0; j < lim; ++j) {
                unsigned lbits = ((const unsigned*)len)[base + j];
                if (__uint_as_float(lbits) >= 10.0f) continue;
                unsigned r = (unsigned)recv[base + j];
                unsigned b = r >> B2SHIFT;
                unsigned slot = startp[b] + (half ? start1[b] : 0u)
                              + atomicAdd(&pos[half][b], 1u);
                srec[slot] = make_uint2((unsigned)send[base + j] | ((r & (B2SIZE - 1)) << 17),
                                        lbits);
                bmap[slot] = (unsigned char)b;
            }
        }
    }
    __syncthreads();

    unsigned total = startp[NB2];
    for (unsigned i = tid; i < total; i += SBLK) {
        unsigned b = bmap[i];
        unsigned g = gbase[b] + (i - startp[b]);
        uint2 rec = srec[i];
        if (g < (unsigned)cap) {
            buckets[(size_t)b * cap + g] = rec;
        } else {
            unsigned o = atomicAdd(ocur, 1u);
            unsigned r = ((unsigned)b << B2SHIFT) | ((rec.x >> 17) & (B2SIZE - 1));
            if (o < ocap) ovrec[o] = make_uint4(r, rec.x & 0x1FFFFu, rec.y, 0u);
        }
    }
}

// cn-resolved parameter class id per node (1 byte).
__global__ void gnb_params(const int* __restrict__ Z, const int* __restrict__ cn,
                           unsigned char* __restrict__ pid, int n_nodes) {
    int i = blockIdx.x * blockDim.x + threadIdx.x;
    if (i >= n_nodes) return;
    int z = Z[i];
    int id = z;
    if (z == 6)      id = (cn[i] <= 3) ? 87 : 88;
    else if (z == 7) id = (cn[i] <= 2) ? 89 : 90;
    pid[i] = (unsigned char)id;
}

__device__ __forceinline__ float gnb_energy_eval(float2 ps, float2 pr, float rlen) {
    float env;
    if (rlen < 8.0f) {
        env = 1.0f;
    } else {
        float x = (rlen - 8.0f) * 0.5f;          // records guarantee x < 1
        float x2 = x * x;
        float x6 = x2 * x2 * x2;
        env = 1.0f - 28.0f * x6 + 48.0f * x6 * x - 21.0f * x6 * x2;
    }
    float sR  = ps.y * pr.y;                     // sqrt(R_ij)
    float C6  = ps.x * pr.x;                     // sqrt(C6_s*C6_r)
    float Rij = sR * sR;
    float R3  = Rij * Rij * Rij;
    float R6  = R3 * R3;
    float r0  = 0.4f * sR + 4.0f;
    float t   = r0 / rlen;
    float t2 = t * t, t4 = t2 * t2, t8 = t4 * t4;
    float t14 = t8 * t4 * t2;
    float fd = 1.0f / (1.0f + 6.0f * t14);
    float rl2 = rlen * rlen;
    float r6 = rl2 * rl2 * rl2;
    return -0.5f * C6 / (R6 + r6) * fd * env;
}

// Main blocks: per (bin,slice) accumulate records into LDS bin (2-replica acc);
// sender params via 1B pid gather + LDS table; uint4 record pairs.
// Tail OVB blocks: drain overflow queue (normally empty). No fences, no flags.
__global__ void __launch_bounds__(256)
gnb_energy(const uint2* __restrict__ buckets, const unsigned* __restrict__ cursor,
           const float2* __restrict__ PT, const unsigned char* __restrict__ pid,
           float* __restrict__ rep, float* __restrict__ ovf,
           const uint4* __restrict__ ovrec, const unsigned* __restrict__ ocur,
           unsigned ocap, int cap, int n_nodes, int nmain) {
    __shared__ float  acc[2][B2SIZE + 8];
    __shared__ float2 p2loc[B2SIZE];
    __shared__ float2 ptab[96];
    const int tid = threadIdx.x;
    const int bid = blockIdx.x;
    const int b   = bid / ES;
    const int rr  = (tid >> 6) & 1;

    if (tid < 91) ptab[tid] = PT[tid];
    if (bid < nmain) {
        for (int i = tid; i < 2 * (B2SIZE + 8); i += 256) acc[0][i] = 0.0f;
        for (int i = tid; i < B2SIZE; i += 256) {
            int node = (b << B2SHIFT) + i;
            p2loc[i] = (node < n_nodes) ? PT[pid[node]] : make_float2(0.f, 0.f);
        }
    }
    __syncthreads();

    if (bid >= nmain) {                   // overflow tail blocks
        unsigned n = *ocur; if (n > ocap) n = ocap;
        unsigned t0 = (unsigned)(bid - nmain) * 256 + tid;
        for (unsigned i = t0; i < n; i += OVB * 256) {
            uint4 rec = ovrec[i];
            float rlen = __uint_as_float(rec.z);
            if (rlen >= 10.0f) continue;
            float e = gnb_energy_eval(ptab[pid[rec.y]], ptab[pid[rec.x]], rlen);
            atomicAdd(&ovf[rec.x], e);
        }
        return;
    }

    const int sl = bid % ES;
    unsigned count = cursor[b];
    if (count > (unsigned)cap) count = (unsigned)cap;
    unsigned seg = (((count + ES - 1) / ES) + 1) & ~1u;   // even -> uint4 pairs
    unsigned st  = (unsigned)sl * seg;
    unsigned en  = st + seg; if (en > count) en = count;

    const uint2* src = buckets + (size_t)b * cap;
    for (unsigned i = st + 2 * tid; i < en; i += 512) {
        if (i + 1 < en) {
            uint4 q = *(const uint4*)(src + i);           // two records, 16B aligned
            {
                unsigned s = q.x & 0x1FFFFu, rl = (q.x >> 17) & (B2SIZE - 1);
                float e = gnb_energy_eval(ptab[pid[s]], p2loc[rl], __uint_as_float(q.y));
                atomicAdd(&acc[rr][rl], e);
            }
            {
                unsigned s = q.z & 0x1FFFFu, rl = (q.z >> 17) & (B2SIZE - 1);
                float e = gnb_energy_eval(ptab[pid[s]], p2loc[rl], __uint_as_float(q.w));
                atomicAdd(&acc[rr][rl], e);
            }
        } else {
            uint2 rec = src[i];
            unsigned s = rec.x & 0x1FFFFu, rl = (rec.x >> 17) & (B2SIZE - 1);
            float e = gnb_energy_eval(ptab[pid[s]], p2loc[rl], __uint_as_float(rec.y));
            atomicAdd(&acc[rr][rl], e);
        }
    }
    __syncthreads();

    float* dst = rep + (size_t)bid * B2SIZE;
    for (int i = tid; i < B2SIZE; i += 256) dst[i] = acc[0][i] + acc[1][i];
}

__global__ void gnb_reduce(const float* __restrict__ rep, const float* __restrict__ ovf,
                           float* __restrict__ out, int n_nodes) {
    int i = blockIdx.x * blockDim.x + threadIdx.x;
    if (i >= n_nodes) return;
    int b = i >> B2SHIFT;
    int j = i & (B2SIZE - 1);
    const float* src = rep + ((size_t)b * ES) * B2SIZE + j;
    float sum = ovf[i];
    #pragma unroll
    for (int s = 0; s < ES; ++s) sum += src[(size_t)s * B2SIZE];
    out[i] = sum;
}

extern "C" void kernel_launch(void* const* d_in, const int* in_sizes, int n_in,
                              void* d_out, int out_size, void* d_ws, size_t ws_size,
                              hipStream_t stream) {
    const int*   Z    = (const int*)d_in[0];
    const int*   eidx = (const int*)d_in[1];
    const float* len  = (const float*)d_in[2];
    float*       out  = (float*)d_out;

    const int n_nodes = in_sizes[0];
    const int n_edges = in_sizes[2];
    const int* send = eidx;
    const int* recv = eidx + n_edges;

    const int NB2 = (n_nodes + B2SIZE - 1) >> B2SHIFT;   // 98 for n=100000
    const int nw  = (n_nodes + 31) >> 5;
    const size_t nwp   = ((size_t)nw + 3) & ~3ull;
    const size_t npidw = (((size_t)n_nodes + 3) / 4 + 3) & ~3ull;

    // ws layout (words): cursor 128 | ocur 8 | cn n | ovf n | PT 192 | isCN | pid | rep | tail
    size_t o_cn   = 136;
    size_t o_ovf  = o_cn + n_nodes;
    size_t o_PT   = o_ovf + n_nodes;
    size_t o_isCN = o_PT + 192;
    size_t o_pid  = o_isCN + nwp;
    size_t o_rep  = (o_pid + npidw + 3) & ~3ull;
    size_t rep_w  = (size_t)NB2 * ES * B2SIZE;
    size_t o_tail = (o_rep + rep_w + 3) & ~3ull;

    char* ws = (char*)d_ws;
    unsigned*      cursor = (unsigned*)ws;
    unsigned*      ocur   = (unsigned*)(ws + 128 * 4);
    int*           cn     = (int*)(ws + o_cn * 4);
    float*         ovf    = (float*)(ws + o_ovf * 4);
    float2*        PT     = (float2*)(ws + o_PT * 4);
    unsigned*      isCN   = (unsigned*)(ws + o_isCN * 4);
    unsigned char* pid    = (unsigned char*)(ws + o_pid * 4);
    float*         rep    = (float*)(ws + o_rep * 4);

    size_t total_words = ws_size / 4;
    size_t avail = total_words > o_tail ? total_words - o_tail : 0;
    size_t ovw = avail / 32;
    unsigned ocap = (unsigned)(ovw / 4);
    long cap = (long)((avail - ovw) / (2 * (size_t)NB2));
    if (cap > n_edges) cap = n_edges;
    if (cap < 0) cap = 0;
    cap &= ~1L;                                   // even -> 16B-aligned record pairs
    uint4* ovrec   = (uint4*)(ws + o_tail * 4);
    uint2* buckets = (uint2*)(ws + (o_tail + (size_t)ocap * 4) * 4);

    const int B = 256;
    int node_blocks = (n_nodes + B - 1) / B;
    int scat_blocks = (n_edges + TILE - 1) / TILE;
    int zero_words  = (int)o_PT;                  // cursor+ocur+cn+ovf
    int nmain = NB2 * ES;

    gnb_init<<<1024, B, 0, stream>>>(Z, isCN, PT, nw, n_nodes, (int*)ws, zero_words);
    gnb_scatter<<<scat_blocks, SBLK, 0, stream>>>(send, recv, len, isCN, cn, buckets,
                                                  cursor, ovrec, ocur, n_edges,
                                                  (int)cap, ocap, NB2);
    gnb_params<<<node_blocks, B, 0, stream>>>(Z, cn, pid, n_nodes);
    gnb_energy<<<nmain + OVB, B, 0, stream>>>(buckets, cursor, PT, pid, rep, ovf,
                                              ovrec, ocur, ocap, (int)cap, n_nodes, nmain);
    gnb_reduce<<<node_blocks, B, 0, stream>>>(rep, ovf, out, n_nodes);
}